// Round 17
// baseline (151.078 us; speedup 1.0000x reference)
//
#include <hip/hip_runtime.h>

typedef float f32x4 __attribute__((ext_vector_type(4)));
typedef short bf16x8 __attribute__((ext_vector_type(8)));

#define AS1 __attribute__((address_space(1)))
#define AS3 __attribute__((address_space(3)))

__device__ __forceinline__ void gl16(const void* g, void* l) {
  __builtin_amdgcn_global_load_lds((const AS1 unsigned int*)g,
                                   (AS3 unsigned int*)l, 16, 0, 0);
}

__device__ __forceinline__ unsigned short f2bf(float f) {
  unsigned u = __float_as_uint(f);
  u = u + 0x7FFFu + ((u >> 16) & 1u);   // RNE
  return (unsigned short)(u >> 16);
}

// ---------------- K2: style (fused) + modulate + demodulate -> bf16
// layout wm[(n*27+k)*64+o][i], row=128B, 16B chunks XOR-swizzled by (o&7).
__global__ __launch_bounds__(256) void k_wmod(const float* __restrict__ s,
                                              const float* __restrict__ sw,
                                              const float* __restrict__ sb,
                                              const float* __restrict__ weight,
                                              unsigned short* __restrict__ wm) {
  int o = blockIdx.x, n = blockIdx.y, t = threadIdx.x;
  int lane = t & 63, wv = t >> 6;
  // ---- fused style: style[i] = sum_k s[n,k]*sw[i,k] + sb[i]
  __shared__ float st4[64][5];
  __shared__ float st[64];
  {
    int i = t >> 2, part = t & 3;
    const float4* swp = (const float4*)(sw + i * 512 + part * 128);
    const float4* sp4 = (const float4*)(s + n * 512 + part * 128);
    float a = 0.f;
#pragma unroll 8
    for (int kk = 0; kk < 32; ++kk) {
      float4 w4 = swp[kk], s4 = sp4[kk];
      a += w4.x * s4.x + w4.y * s4.y + w4.z * s4.z + w4.w * s4.w;
    }
    st4[i][part] = a;
  }
  __syncthreads();
  if (t < 64) st[t] = st4[t][0] + st4[t][1] + st4[t][2] + st4[t][3] + sb[t];
  __syncthreads();

  const float* wp = weight + o * 1728;   // [i][27]
  float v[7];
  float ss = 0.f;
#pragma unroll
  for (int j = 0; j < 7; ++j) {
    int idx = t + j * 256;
    float w = 0.f;
    if (idx < 1728) {
      int i = idx / 27;
      w = wp[idx] * st[i];
    }
    v[j] = w;
    ss += w * w;
  }
#pragma unroll
  for (int off = 32; off > 0; off >>= 1) ss += __shfl_down(ss, off);
  __shared__ float red[4];
  if (lane == 0) red[wv] = ss;
  __syncthreads();
  float total = red[0] + red[1] + red[2] + red[3];
  float dm = 1.0f / sqrtf(total + 1e-8f);
#pragma unroll
  for (int j = 0; j < 7; ++j) {
    int idx = t + j * 256;
    if (idx < 1728) {
      int i = idx / 27, k = idx - i * 27;
      int g = (n * 27 + k) * 64 + o;
      wm[g * 64 + (((i >> 3) ^ (o & 7)) << 3) + (i & 7)] = f2bf(v[j] * dm);
    }
  }
}

// ---------------- K3: x[N][64][48^3] fp32 -> xT[(n*110592+p)][i] bf16,
// 16B chunks XOR-swizzled by (p&7). 256p x 64i per block; float4 loads,
// coalesced uint4 stores.
__global__ __launch_bounds__(256) void k_xpose(const float* __restrict__ x,
                                               unsigned short* __restrict__ xT) {
  __shared__ unsigned tile[256][33];   // [p][i-pair]
  int n = blockIdx.y;
  int p0 = blockIdx.x * 256;
  int t = threadIdx.x;
  int wv = t >> 6, lane = t & 63;
  const float* xb = x + (size_t)n * 64 * 110592 + p0 + 4 * lane;
#pragma unroll
  for (int c = 0; c < 8; ++c) {
    int i2 = wv + 4 * c;               // i-pair 0..31
    const float4 a = *(const float4*)(xb + (size_t)(2 * i2) * 110592);
    const float4 b = *(const float4*)(xb + (size_t)(2 * i2 + 1) * 110592);
    tile[4 * lane + 0][i2] = (unsigned)f2bf(a.x) | ((unsigned)f2bf(b.x) << 16);
    tile[4 * lane + 1][i2] = (unsigned)f2bf(a.y) | ((unsigned)f2bf(b.y) << 16);
    tile[4 * lane + 2][i2] = (unsigned)f2bf(a.z) | ((unsigned)f2bf(b.z) << 16);
    tile[4 * lane + 3][i2] = (unsigned)f2bf(a.w) | ((unsigned)f2bf(b.w) << 16);
  }
  __syncthreads();
  uint4* dst = (uint4*)xT;
  int sl = t & 7;                      // store slot
#pragma unroll
  for (int pass = 0; pass < 8; ++pass) {
    int p = (t >> 3) + 32 * pass;
    int c = sl ^ (p & 7);              // data chunk living at slot sl
    uint4 u;
    u.x = tile[p][4 * c + 0];
    u.y = tile[p][4 * c + 1];
    u.z = tile[p][4 * c + 2];
    u.w = tile[p][4 * c + 3];
    dst[(size_t)(n * 110592 + p0 + p) * 8 + sl] = u;
  }
}

// ---------------- K4: implicit-GEMM conv (R10 skeleton + STATIC two-group
// tap stagger). 256p x 64o per block, 4 waves, wave tile 64o x 64p. B slab
// (46KB) only LDS -> 3 blocks/CU = 12 waves. A in REGISTERS via global/L1,
// full-tap dbuf one step ahead. Waves 0-1 walk each kd's taps 0..8; waves
// 2-3 walk 4..8,0..3 (all indices compile-time -> no VGPR cliff). The ~4-tap
// phase offset lets one group's MFMA cluster cover the other group's
// ds_read/A-load phase (convoy breaker, m114 mechanism).
// Taps barrier-free; 2 barriers per kd. XCD swizzle (1656 = 8*207).
__global__ __launch_bounds__(256) void k_conv(const unsigned short* __restrict__ xT,
                                              const unsigned short* __restrict__ wm,
                                              const float* __restrict__ bias,
                                              float* __restrict__ out) {
  __shared__ uint4 Bl4[46080 / 16];     // 360 rows x 128B
  char* Bl = (char*)Bl4;

  int bid = blockIdx.x;                       // 0..1655 dispatch slot
  int orig = (bid & 7) * 207 + (bid >> 3);    // chunked XCD swizzle (bijective)
  int n = orig / 414;
  int pb = orig - n * 414;
  int p0 = pb * 256;

  int t = threadIdx.x;
  int lane = t & 63, wv = t >> 6;
  int l15 = lane & 15, lhi = lane >> 4;
  f32x4 acc[4][4] = {};

  const char* xb = (const char*)xT + ((size_t)(n * 110592 + p0)) * 128;
  const char* wb = (const char*)wm + (size_t)n * 27 * 8192;

  // per-lane A fragment byte offsets within one 8KB tap tile (swizzle baked
  // into wm layout by k_wmod)
  int aoff[8];
#pragma unroll
  for (int m = 0; m < 4; ++m)
#pragma unroll
    for (int ih = 0; ih < 2; ++ih) {
      int orow = m * 16 + l15;
      int c = lhi + ih * 4;
      aoff[m * 2 + ih] = orow * 128 + ((c ^ (orow & 7)) << 4);
    }

  bf16x8 aA[8], aB[8];
  // prologue: this group's first tile (tap 0 or tap 4 of kd0) into aA
  {
    const char* ap0 = wb + (size_t)((wv < 2) ? 0 : 4) * 8192;
#pragma unroll
    for (int j = 0; j < 8; ++j) aA[j] = *(const bf16x8*)(ap0 + aoff[j]);
  }

  // One step: prefetch NEXT tile of this group's sequence, then MFMA current.
  // S = global step 0..26; F = group tap offset. All indices constant-fold.
#define TAPX(CUR, NXT, S, F)                                                   \
  do {                                                                         \
    if ((S) + 1 < 27) {                                                        \
      const char* ap_ = wb +                                                   \
          (size_t)((((S) + 1) / 9) * 9 + ((((S) + 1) % 9 + (F)) % 9)) * 8192;  \
      _Pragma("unroll") for (int jj = 0; jj < 8; ++jj)                         \
          NXT[jj] = *(const bf16x8*)(ap_ + aoff[jj]);                          \
    }                                                                          \
    __builtin_amdgcn_sched_barrier(0);                                         \
    const int tp_ = ((S) % 9 + (F)) % 9;                                       \
    const int kh_ = tp_ / 3, kw_ = tp_ % 3;                                    \
    const int rbase_ = wv * 64 + kh_ * 48 + kw_;                               \
    _Pragma("unroll") for (int ih = 0; ih < 2; ++ih) {                         \
      int c_ = lhi + ih * 4;                                                   \
      bf16x8 b_[4];                                                            \
      _Pragma("unroll") for (int q = 0; q < 4; ++q) {                          \
        int r_ = rbase_ + q * 16 + l15;                                        \
        b_[q] = *(const bf16x8*)(Bl + r_ * 128 + ((c_ ^ (r_ & 7)) << 4));      \
      }                                                                        \
      __builtin_amdgcn_s_setprio(1);                                           \
      _Pragma("unroll") for (int m = 0; m < 4; ++m)                            \
          _Pragma("unroll") for (int q = 0; q < 4; ++q)                        \
              acc[m][q] = __builtin_amdgcn_mfma_f32_16x16x32_bf16(             \
                  CUR[m * 2 + ih], b_[q], acc[m][q], 0, 0, 0);                 \
      __builtin_amdgcn_s_setprio(0);                                           \
    }                                                                          \
  } while (0)

#define STEPX(S, F)                                                            \
  do {                                                                         \
    if (((S) & 1) == 0) TAPX(aA, aB, S, F);                                    \
    else                TAPX(aB, aA, S, F);                                    \
  } while (0)

#define NINE(KD, F)                                                            \
  do {                                                                         \
    STEPX((KD) * 9 + 0, F); STEPX((KD) * 9 + 1, F); STEPX((KD) * 9 + 2, F);    \
    STEPX((KD) * 9 + 3, F); STEPX((KD) * 9 + 4, F); STEPX((KD) * 9 + 5, F);    \
    STEPX((KD) * 9 + 6, F); STEPX((KD) * 9 + 7, F); STEPX((KD) * 9 + 8, F);    \
  } while (0)

#pragma unroll
  for (int kd = 0; kd < 3; ++kd) {
    if (kd) __builtin_amdgcn_s_barrier();  // all waves done reading Bl
    const char* src = xb + (size_t)kd * (2304 * 128);
    for (int cc = wv; cc < 45; cc += 4)
      gl16(src + cc * 1024 + lane * 16, Bl + cc * 1024);
    asm volatile("s_waitcnt vmcnt(0)" ::: "memory");  // B slab complete
    __builtin_amdgcn_s_barrier();
    __builtin_amdgcn_sched_barrier(0);
    if (wv < 2) {
      NINE(kd, 0);
    } else {
      NINE(kd, 4);
    }
  }
#undef NINE
#undef STEPX
#undef TAPX

  float bv[4][4];
#pragma unroll
  for (int m = 0; m < 4; ++m)
#pragma unroll
    for (int r = 0; r < 4; ++r) bv[m][r] = bias[m * 16 + lhi * 4 + r];

  float* ob = out + (size_t)n * 64 * 97336;
#pragma unroll
  for (int q = 0; q < 4; ++q) {
    int p = p0 + wv * 64 + q * 16 + l15;
    int d = p / 2304;
    int rem = p - d * 2304;
    int h = rem / 48;
    int w = rem - h * 48;
    if (h < 46 && w < 46) {  // d < 46 guaranteed: p <= 105983
      int base = d * 2116 + h * 46 + w;
#pragma unroll
      for (int m = 0; m < 4; ++m)
#pragma unroll
        for (int r = 0; r < 4; ++r) {
          int o = m * 16 + lhi * 4 + r;
          ob[(size_t)o * 97336 + base] = acc[m][q][r] + bv[m][r];
        }
    }
  }
}

extern "C" void kernel_launch(void* const* d_in, const int* in_sizes, int n_in,
                              void* d_out, int out_size, void* d_ws, size_t ws_size,
                              hipStream_t stream) {
  const float* x    = (const float*)d_in[0];
  const float* s    = (const float*)d_in[1];
  const float* sw   = (const float*)d_in[2];
  const float* sb   = (const float*)d_in[3];
  const float* wt   = (const float*)d_in[4];
  const float* bias = (const float*)d_in[5];
  float* out = (float*)d_out;

  // ws layout: [0,1024) unused; [1024, 885760) wm bf16 (4*27*64*64);
  // [885760, +57,225,472) xT bf16 incl. tail pad for shift overreach.
  unsigned short* wm    = (unsigned short*)((char*)d_ws + 1024);
  unsigned short* xT    = (unsigned short*)((char*)d_ws + 1024 + 884736);

  hipLaunchKernelGGL(k_wmod, dim3(64, 4), dim3(256), 0, stream, s, sw, sb, wt, wm);
  hipLaunchKernelGGL(k_xpose, dim3(432, 4), dim3(256), 0, stream, x, xT);
  hipLaunchKernelGGL(k_conv, dim3(1656), dim3(256), 0, stream, xT, wm, bias, out);
}

// Round 18
// 136.497 us; speedup vs baseline: 1.1068x; 1.1068x over previous
//
#include <hip/hip_runtime.h>

typedef float f32x4 __attribute__((ext_vector_type(4)));
typedef short bf16x8 __attribute__((ext_vector_type(8)));

#define AS1 __attribute__((address_space(1)))
#define AS3 __attribute__((address_space(3)))

__device__ __forceinline__ void gl16(const void* g, void* l) {
  __builtin_amdgcn_global_load_lds((const AS1 unsigned int*)g,
                                   (AS3 unsigned int*)l, 16, 0, 0);
}

__device__ __forceinline__ unsigned short f2bf(float f) {
  unsigned u = __float_as_uint(f);
  u = u + 0x7FFFu + ((u >> 16) & 1u);   // RNE
  return (unsigned short)(u >> 16);
}

// ---------------- K2: style (fused) + modulate + demodulate -> bf16
// layout wm[(n*27+k)*64+o][i], row=128B, 16B chunks XOR-swizzled by (o&7).
__global__ __launch_bounds__(256) void k_wmod(const float* __restrict__ s,
                                              const float* __restrict__ sw,
                                              const float* __restrict__ sb,
                                              const float* __restrict__ weight,
                                              unsigned short* __restrict__ wm) {
  int o = blockIdx.x, n = blockIdx.y, t = threadIdx.x;
  int lane = t & 63, wv = t >> 6;
  // ---- fused style: style[i] = sum_k s[n,k]*sw[i,k] + sb[i]
  __shared__ float st4[64][5];
  __shared__ float st[64];
  {
    int i = t >> 2, part = t & 3;
    const float4* swp = (const float4*)(sw + i * 512 + part * 128);
    const float4* sp4 = (const float4*)(s + n * 512 + part * 128);
    float a = 0.f;
#pragma unroll 8
    for (int kk = 0; kk < 32; ++kk) {
      float4 w4 = swp[kk], s4 = sp4[kk];
      a += w4.x * s4.x + w4.y * s4.y + w4.z * s4.z + w4.w * s4.w;
    }
    st4[i][part] = a;
  }
  __syncthreads();
  if (t < 64) st[t] = st4[t][0] + st4[t][1] + st4[t][2] + st4[t][3] + sb[t];
  __syncthreads();

  const float* wp = weight + o * 1728;   // [i][27]
  float v[7];
  float ss = 0.f;
#pragma unroll
  for (int j = 0; j < 7; ++j) {
    int idx = t + j * 256;
    float w = 0.f;
    if (idx < 1728) {
      int i = idx / 27;
      w = wp[idx] * st[i];
    }
    v[j] = w;
    ss += w * w;
  }
#pragma unroll
  for (int off = 32; off > 0; off >>= 1) ss += __shfl_down(ss, off);
  __shared__ float red[4];
  if (lane == 0) red[wv] = ss;
  __syncthreads();
  float total = red[0] + red[1] + red[2] + red[3];
  float dm = 1.0f / sqrtf(total + 1e-8f);
#pragma unroll
  for (int j = 0; j < 7; ++j) {
    int idx = t + j * 256;
    if (idx < 1728) {
      int i = idx / 27, k = idx - i * 27;
      int g = (n * 27 + k) * 64 + o;
      wm[g * 64 + (((i >> 3) ^ (o & 7)) << 3) + (i & 7)] = f2bf(v[j] * dm);
    }
  }
}

// ---------------- K3: x[N][64][48^3] fp32 -> xT[(n*110592+p)][i] bf16,
// 16B chunks XOR-swizzled by (p&7). 256p x 64i per block; float4 loads,
// coalesced uint4 stores.
__global__ __launch_bounds__(256) void k_xpose(const float* __restrict__ x,
                                               unsigned short* __restrict__ xT) {
  __shared__ unsigned tile[256][33];   // [p][i-pair]
  int n = blockIdx.y;
  int p0 = blockIdx.x * 256;
  int t = threadIdx.x;
  int wv = t >> 6, lane = t & 63;
  const float* xb = x + (size_t)n * 64 * 110592 + p0 + 4 * lane;
#pragma unroll
  for (int c = 0; c < 8; ++c) {
    int i2 = wv + 4 * c;               // i-pair 0..31
    const float4 a = *(const float4*)(xb + (size_t)(2 * i2) * 110592);
    const float4 b = *(const float4*)(xb + (size_t)(2 * i2 + 1) * 110592);
    tile[4 * lane + 0][i2] = (unsigned)f2bf(a.x) | ((unsigned)f2bf(b.x) << 16);
    tile[4 * lane + 1][i2] = (unsigned)f2bf(a.y) | ((unsigned)f2bf(b.y) << 16);
    tile[4 * lane + 2][i2] = (unsigned)f2bf(a.z) | ((unsigned)f2bf(b.z) << 16);
    tile[4 * lane + 3][i2] = (unsigned)f2bf(a.w) | ((unsigned)f2bf(b.w) << 16);
  }
  __syncthreads();
  uint4* dst = (uint4*)xT;
  int sl = t & 7;                      // store slot
#pragma unroll
  for (int pass = 0; pass < 8; ++pass) {
    int p = (t >> 3) + 32 * pass;
    int c = sl ^ (p & 7);              // data chunk living at slot sl
    uint4 u;
    u.x = tile[p][4 * c + 0];
    u.y = tile[p][4 * c + 1];
    u.z = tile[p][4 * c + 2];
    u.w = tile[p][4 * c + 3];
    dst[(size_t)(n * 110592 + p0 + p) * 8 + sl] = u;
  }
}

// ---------------- K4: implicit-GEMM conv (R10 champion, micro-tuned tap:
// no setprio, ds-first ordering). 256p x 64o per block, 4 waves, wave tile
// 64o x 64p. B slab (46KB) only LDS -> 3 blocks/CU = 12 waves. A in
// REGISTERS via global/L1, full-tap dbuf one tap ahead, prefetch issued
// MID-TAP (after MFMA ih0) so tap-front ds_reads aren't queued behind 8
// global loads. Taps barrier-free; 2 barriers per kd. XCD swizzle (1656).
__global__ __launch_bounds__(256) void k_conv(const unsigned short* __restrict__ xT,
                                              const unsigned short* __restrict__ wm,
                                              const float* __restrict__ bias,
                                              float* __restrict__ out) {
  __shared__ uint4 Bl4[46080 / 16];     // 360 rows x 128B
  char* Bl = (char*)Bl4;

  int bid = blockIdx.x;                       // 0..1655 dispatch slot
  int orig = (bid & 7) * 207 + (bid >> 3);    // chunked XCD swizzle (bijective)
  int n = orig / 414;
  int pb = orig - n * 414;
  int p0 = pb * 256;

  int t = threadIdx.x;
  int lane = t & 63, wv = t >> 6;
  int l15 = lane & 15, lhi = lane >> 4;
  f32x4 acc[4][4] = {};

  const char* xb = (const char*)xT + ((size_t)(n * 110592 + p0)) * 128;
  const char* wb = (const char*)wm + (size_t)n * 27 * 8192;

  // per-lane A fragment byte offsets within one 8KB tap tile (swizzle baked
  // into wm layout by k_wmod)
  int aoff[8];
#pragma unroll
  for (int m = 0; m < 4; ++m)
#pragma unroll
    for (int ih = 0; ih < 2; ++ih) {
      int orow = m * 16 + l15;
      int c = lhi + ih * 4;
      aoff[m * 2 + ih] = orow * 128 + ((c ^ (orow & 7)) << 4);
    }

  bf16x8 aA[8], aB[8];
  // prologue: tap 0 A fragments into aA
#pragma unroll
  for (int j = 0; j < 8; ++j) aA[j] = *(const bf16x8*)(wb + aoff[j]);

  // One tap: ds ih0 -> MFMA ih0 -> prefetch A(s+1) (pinned) -> ds ih1 ->
  // MFMA ih1. Prefetch retires under ih1 + next tap front (~500cy).
#define TAP(CUR, NXT, S, TP)                                                   \
  do {                                                                         \
    const int kh_ = (TP) / 3, kw_ = (TP) % 3;                                  \
    const int rbase_ = wv * 64 + kh_ * 48 + kw_;                               \
    bf16x8 b_[4];                                                              \
    _Pragma("unroll") for (int q = 0; q < 4; ++q) {                            \
      int r_ = rbase_ + q * 16 + l15;                                          \
      b_[q] = *(const bf16x8*)(Bl + r_ * 128 + ((lhi ^ (r_ & 7)) << 4));       \
    }                                                                          \
    _Pragma("unroll") for (int m = 0; m < 4; ++m)                              \
        _Pragma("unroll") for (int q = 0; q < 4; ++q)                          \
            acc[m][q] = __builtin_amdgcn_mfma_f32_16x16x32_bf16(               \
                CUR[m * 2 + 0], b_[q], acc[m][q], 0, 0, 0);                    \
    if ((S) + 1 < 27) {                                                        \
      const char* ap_ = wb + (size_t)((S) + 1) * 8192;                         \
      _Pragma("unroll") for (int jj = 0; jj < 8; ++jj)                         \
          NXT[jj] = *(const bf16x8*)(ap_ + aoff[jj]);                          \
    }                                                                          \
    __builtin_amdgcn_sched_barrier(0);                                         \
    _Pragma("unroll") for (int q = 0; q < 4; ++q) {                            \
      int r_ = rbase_ + q * 16 + l15;                                          \
      b_[q] = *(const bf16x8*)(Bl + r_ * 128 + (((lhi + 4) ^ (r_ & 7)) << 4)); \
    }                                                                          \
    _Pragma("unroll") for (int m = 0; m < 4; ++m)                              \
        _Pragma("unroll") for (int q = 0; q < 4; ++q)                          \
            acc[m][q] = __builtin_amdgcn_mfma_f32_16x16x32_bf16(               \
                CUR[m * 2 + 1], b_[q], acc[m][q], 0, 0, 0);                    \
  } while (0)

#pragma unroll
  for (int kd = 0; kd < 3; ++kd) {
    if (kd) __builtin_amdgcn_s_barrier();  // all waves done reading Bl
    const char* src = xb + (size_t)kd * (2304 * 128);
    for (int cc = wv; cc < 45; cc += 4)
      gl16(src + cc * 1024 + lane * 16, Bl + cc * 1024);
    asm volatile("s_waitcnt vmcnt(0)" ::: "memory");  // B slab complete
    __builtin_amdgcn_s_barrier();
    __builtin_amdgcn_sched_barrier(0);
#pragma unroll
    for (int tp = 0; tp < 9; ++tp) {
      const int s = kd * 9 + tp;
      if ((s & 1) == 0) TAP(aA, aB, s, tp);
      else              TAP(aB, aA, s, tp);
    }
  }
#undef TAP

  float bv[4][4];
#pragma unroll
  for (int m = 0; m < 4; ++m)
#pragma unroll
    for (int r = 0; r < 4; ++r) bv[m][r] = bias[m * 16 + lhi * 4 + r];

  float* ob = out + (size_t)n * 64 * 97336;
#pragma unroll
  for (int q = 0; q < 4; ++q) {
    int p = p0 + wv * 64 + q * 16 + l15;
    int d = p / 2304;
    int rem = p - d * 2304;
    int h = rem / 48;
    int w = rem - h * 48;
    if (h < 46 && w < 46) {  // d < 46 guaranteed: p <= 105983
      int base = d * 2116 + h * 46 + w;
#pragma unroll
      for (int m = 0; m < 4; ++m)
#pragma unroll
        for (int r = 0; r < 4; ++r) {
          int o = m * 16 + lhi * 4 + r;
          ob[(size_t)o * 97336 + base] = acc[m][q][r] + bv[m][r];
        }
    }
  }
}

extern "C" void kernel_launch(void* const* d_in, const int* in_sizes, int n_in,
                              void* d_out, int out_size, void* d_ws, size_t ws_size,
                              hipStream_t stream) {
  const float* x    = (const float*)d_in[0];
  const float* s    = (const float*)d_in[1];
  const float* sw   = (const float*)d_in[2];
  const float* sb   = (const float*)d_in[3];
  const float* wt   = (const float*)d_in[4];
  const float* bias = (const float*)d_in[5];
  float* out = (float*)d_out;

  // ws layout: [0,1024) unused; [1024, 885760) wm bf16 (4*27*64*64);
  // [885760, +57,225,472) xT bf16 incl. tail pad for shift overreach.
  unsigned short* wm    = (unsigned short*)((char*)d_ws + 1024);
  unsigned short* xT    = (unsigned short*)((char*)d_ws + 1024 + 884736);

  hipLaunchKernelGGL(k_wmod, dim3(64, 4), dim3(256), 0, stream, s, sw, sb, wt, wm);
  hipLaunchKernelGGL(k_xpose, dim3(432, 4), dim3(256), 0, stream, x, xT);
  hipLaunchKernelGGL(k_conv, dim3(1656), dim3(256), 0, stream, xT, wm, bias, out);
}